// Round 2
// baseline (667.539 us; speedup 1.0000x reference)
//
#include <hip/hip_runtime.h>

// Entropic Sinkhorn EMD, B=2, N=4096, D=3, EPS=0.1, 20 iters.
// Round-2 structure: j-points live in REGISTERS (8 float4/lane), i-points
// stream via wave-uniform s_load. Inner loop has no LDS / vector-mem ops.
// All exponent math pre-scaled by log2(e) so exp2f == bare v_exp_f32.
// C expanded: 10*(g - C) + SHIFT = h2_j + s2_i + 20*pi.pj  (in log2 units),
//   h2_j = (10 g_j + SHIFT)*L2E - 10*L2E*|pj|^2 ,  s2_i = -10*L2E*|pi|^2.

#define N   4096
#define NT  512     // 8 waves/block
#define IC  16      // rows per block -> grid.x = 256
#define JPL 8       // j's per lane (512 per wave, 4096 per block)

constexpr float EPS_F = 0.1f;
constexpr float SHIFT = 60.0f;
constexpr float LOG_A = -8.317766166719343f;   // -log(4096)
constexpr float L2E   = 1.4426950408889634f;   // log2(e)
constexpr float C10L  = 14.426950408889634f;   // 10*L2E
constexpr float C20L  = 28.853900817779268f;   // 20*L2E
constexpr float NLN2T = -0.06931471805599453f; // -ln2/10  (w -> |p|^2)
constexpr float LN2   = 0.6931471805599453f;

// Pack {x,y,z, -10*L2E*|p|^2} for both clouds; zero f,g and out.
__global__ __launch_bounds__(256) void prep_kernel(
    const float* __restrict__ gen, const float* __restrict__ gt,
    float4* __restrict__ genPack, float4* __restrict__ gtPack,
    float* __restrict__ fg, float* __restrict__ out)
{
    int t = blockIdx.x * 256 + threadIdx.x;   // 0 .. 16383
    int cloud = t >> 13;                      // 0=gen, 1=gt
    int idx   = t & 8191;                     // b*N + j
    const float* src = cloud ? gt : gen;
    float x = src[idx * 3 + 0];
    float y = src[idx * 3 + 1];
    float z = src[idx * 3 + 2];
    float w = -C10L * fmaf(z, z, fmaf(y, y, x * x));
    float4 p = make_float4(x, y, z, w);
    (cloud ? gtPack : genPack)[idx] = p;
    fg[t] = 0.0f;                             // f[2][N] then g[2][N] contiguous
    if (t == 0) out[0] = 0.0f;
}

// One half-sweep: dualRowOut_i = EPS*(LOG_A + SHIFT - ln sum_j 2^{arg2})
__global__ __launch_bounds__(NT) void sweep_kernel(
    const float4* __restrict__ rowPack,   // [2][N]
    const float4* __restrict__ colPack,   // [2][N]
    const float*  __restrict__ dualCol,   // [2][N]
    float*        __restrict__ dualRowOut)
{
    __shared__ float sPart[IC][8];

    const int b    = blockIdx.y;
    const int tid  = threadIdx.x;
    const int wave = tid >> 6;
    const int lane = tid & 63;
    const int jbase = wave * (64 * JPL) + lane;     // j = jbase + 64*m

    // Load this lane's 8 j-points into registers (coalesced float4 + dword).
    float xj[JPL], yj[JPL], zj[JPL], h2[JPL];
    {
        const float4* cp = colPack + (size_t)b * N;
        const float*  dc = dualCol + (size_t)b * N;
        #pragma unroll
        for (int m = 0; m < JPL; ++m) {
            float4 p = cp[jbase + 64 * m];
            float  g = dc[jbase + 64 * m];
            xj[m] = p.x; yj[m] = p.y; zj[m] = p.z;
            h2[m] = fmaf(g, C10L, (SHIFT * L2E) + p.w);
        }
    }

    const float4* rp = rowPack + (size_t)b * N + (size_t)blockIdx.x * IC;

    #pragma unroll 2
    for (int ii = 0; ii < IC; ++ii) {
        float4 q = rp[ii];                 // wave-uniform -> s_load_dwordx4
        float X = q.x * C20L;
        float Y = q.y * C20L;
        float Z = q.z * C20L;
        float s2 = q.w;                    // -10*L2E*|pi|^2
        float a0 = 0.f, a1 = 0.f, a2 = 0.f, a3 = 0.f;
        #pragma unroll
        for (int m = 0; m < JPL; m += 4) {
            a0 += exp2f(fmaf(X, xj[m+0], fmaf(Y, yj[m+0], fmaf(Z, zj[m+0], h2[m+0] + s2))));
            a1 += exp2f(fmaf(X, xj[m+1], fmaf(Y, yj[m+1], fmaf(Z, zj[m+1], h2[m+1] + s2))));
            a2 += exp2f(fmaf(X, xj[m+2], fmaf(Y, yj[m+2], fmaf(Z, zj[m+2], h2[m+2] + s2))));
            a3 += exp2f(fmaf(X, xj[m+3], fmaf(Y, yj[m+3], fmaf(Z, zj[m+3], h2[m+3] + s2))));
        }
        float sum = (a0 + a1) + (a2 + a3);
        sum += __shfl_xor(sum, 1);
        sum += __shfl_xor(sum, 2);
        sum += __shfl_xor(sum, 4);
        sum += __shfl_xor(sum, 8);
        sum += __shfl_xor(sum, 16);
        sum += __shfl_xor(sum, 32);
        if (lane == 0) sPart[ii][wave] = sum;
    }
    __syncthreads();

    if (tid < IC) {
        float t = 0.f;
        #pragma unroll
        for (int w = 0; w < 8; ++w) t += sPart[tid][w];
        float ln_sum = log2f(t) * LN2;
        dualRowOut[(size_t)b * N + (size_t)blockIdx.x * IC + tid] =
            EPS_F * (LOG_A + SHIFT - ln_sum);
    }
}

// loss += 0.5 * sum_ij exp((f_i + g_j - C_ij)/EPS) * C_ij
__global__ __launch_bounds__(NT) void loss_kernel(
    const float4* __restrict__ rowPack,   // gen pack
    const float4* __restrict__ colPack,   // gt pack
    const float*  __restrict__ f,         // [2][N]
    const float*  __restrict__ g,         // [2][N]
    float*        __restrict__ out)
{
    const int b    = blockIdx.y;
    const int tid  = threadIdx.x;
    const int wave = tid >> 6;
    const int lane = tid & 63;
    const int jbase = wave * (64 * JPL) + lane;

    float xj[JPL], yj[JPL], zj[JPL], rj[JPL], G2[JPL];
    {
        const float4* cp = colPack + (size_t)b * N;
        const float*  gc = g + (size_t)b * N;
        #pragma unroll
        for (int m = 0; m < JPL; ++m) {
            float4 p = cp[jbase + 64 * m];
            float  gv = gc[jbase + 64 * m];
            xj[m] = p.x; yj[m] = p.y; zj[m] = p.z;
            rj[m] = p.w * NLN2T;          // |pj|^2
            G2[m] = gv * C10L;
        }
    }

    const float4* rp = rowPack + (size_t)b * N + (size_t)blockIdx.x * IC;
    const float*  fp = f + (size_t)b * N + (size_t)blockIdx.x * IC;

    float acc0 = 0.f, acc1 = 0.f;
    #pragma unroll 2
    for (int ii = 0; ii < IC; ++ii) {
        float4 q = rp[ii];                 // uniform
        float ri = q.w * NLN2T;            // |pi|^2
        float F2 = fp[ii] * C10L;          // uniform
        #pragma unroll
        for (int m = 0; m < JPL; m += 2) {
            {
                float d  = fmaf(q.x, xj[m], fmaf(q.y, yj[m], q.z * zj[m]));
                float cc = fmaf(-2.f, d, ri + rj[m]);
                float p  = exp2f(fmaf(cc, -C10L, F2 + G2[m]));
                acc0 = fmaf(p, cc, acc0);
            }
            {
                float d  = fmaf(q.x, xj[m+1], fmaf(q.y, yj[m+1], q.z * zj[m+1]));
                float cc = fmaf(-2.f, d, ri + rj[m+1]);
                float p  = exp2f(fmaf(cc, -C10L, F2 + G2[m+1]));
                acc1 = fmaf(p, cc, acc1);
            }
        }
    }
    float acc = acc0 + acc1;
    acc += __shfl_xor(acc, 1);
    acc += __shfl_xor(acc, 2);
    acc += __shfl_xor(acc, 4);
    acc += __shfl_xor(acc, 8);
    acc += __shfl_xor(acc, 16);
    acc += __shfl_xor(acc, 32);
    if (lane == 0) atomicAdd(out, acc * 0.5f);
}

extern "C" void kernel_launch(void* const* d_in, const int* in_sizes, int n_in,
                              void* d_out, int out_size, void* d_ws, size_t ws_size,
                              hipStream_t stream) {
    const float* gen = (const float*)d_in[0];
    const float* gt  = (const float*)d_in[1];
    float* out = (float*)d_out;

    char* ws = (char*)d_ws;
    float4* genPack = (float4*)ws;                       // 128 KB
    float4* gtPack  = (float4*)(ws + 128 * 1024);        // 128 KB
    float*  f       = (float*)(ws + 256 * 1024);         // 32 KB
    float*  g       = f + 2 * N;                         // (contiguous with f)

    prep_kernel<<<dim3(16384 / 256), 256, 0, stream>>>(gen, gt, genPack, gtPack, f, out);

    const dim3 grid(N / IC, 2);   // 256 x 2 = 512 blocks
    for (int it = 0; it < 20; ++it) {
        // f update: rows = gen, cols = gt, reads g, writes f
        sweep_kernel<<<grid, NT, 0, stream>>>(genPack, gtPack, g, f);
        // g update: rows = gt, cols = gen, reads f, writes g
        sweep_kernel<<<grid, NT, 0, stream>>>(gtPack, genPack, f, g);
    }
    loss_kernel<<<grid, NT, 0, stream>>>(genPack, gtPack, f, g, out);
}